// Round 3
// baseline (1266.756 us; speedup 1.0000x reference)
//
#include <hip/hip_runtime.h>

// MultiHeadAttention: v(8,1024,512) fp32, pad(8,1,1,1024) int, W1(512,2048), b1(2048),
// W2(8192,512), b2(512) -> out (8,1024,512) fp32 ++ attn (8,16,1024,1024) fp32.
// All matmuls in bf16 MFMA 16x16x32, fp32 accumulate.

typedef __attribute__((ext_vector_type(8))) short bf16x8;
typedef __attribute__((ext_vector_type(4))) float f32x4;
typedef __attribute__((ext_vector_type(4))) unsigned short u16x4;

__device__ __forceinline__ unsigned short f2bf(float f) {
  unsigned u = __builtin_bit_cast(unsigned, f);
  u += 0x7FFFu + ((u >> 16) & 1u);   // RTN-even
  return (unsigned short)(u >> 16);
}

__device__ __forceinline__ void gload_lds16(const unsigned short* g, unsigned short* l) {
  __builtin_amdgcn_global_load_lds(
      (const __attribute__((address_space(1))) unsigned int*)(g),
      (__attribute__((address_space(3))) unsigned int*)(l), 16, 0, 0);
}

// ---------------- preprocessing ----------------

__global__ void cvt_bf16_kernel(const float* __restrict__ in,
                                unsigned short* __restrict__ out, int n4) {
  int i = blockIdx.x * blockDim.x + threadIdx.x;
  if (i >= n4) return;
  f32x4 v = reinterpret_cast<const f32x4*>(in)[i];
  u16x4 o;
#pragma unroll
  for (int j = 0; j < 4; ++j) o[j] = f2bf(v[j]);
  reinterpret_cast<u16x4*>(out)[i] = o;
}

// in fp32 [R][C] -> out bf16 [C][R]
__global__ void transpose_cvt_kernel(const float* __restrict__ in,
                                     unsigned short* __restrict__ out,
                                     int R, int C) {
  __shared__ float tile[32][33];
  int c0 = blockIdx.x * 32, r0 = blockIdx.y * 32;
  int tx = threadIdx.x & 31, ty = threadIdx.x >> 5;
#pragma unroll
  for (int i = ty; i < 32; i += 8)
    tile[i][tx] = in[(size_t)(r0 + i) * C + (c0 + tx)];
  __syncthreads();
#pragma unroll
  for (int i = ty; i < 32; i += 8)
    out[(size_t)(c0 + i) * R + (r0 + tx)] = f2bf(tile[tx][i]);
}

// ---------------- GEMM1: kq = v @ W1 + b1 ----------------
__launch_bounds__(256)
__global__ void gemm1_kernel(const unsigned short* __restrict__ vbf,
                             const unsigned short* __restrict__ w1t,
                             const float* __restrict__ b1,
                             unsigned short* __restrict__ q_ws,
                             unsigned short* __restrict__ k_ws) {
  const int m0 = blockIdx.y * 128, n0 = blockIdx.x * 128;
  const int w = threadIdx.x >> 6, l = threadIdx.x & 63;
  const int wr = w >> 1, wc = w & 1, lr = l & 15, lg = l >> 4;
  f32x4 acc[4][4];
#pragma unroll
  for (int mi = 0; mi < 4; ++mi)
#pragma unroll
    for (int ni = 0; ni < 4; ++ni) acc[mi][ni] = (f32x4){0.f, 0.f, 0.f, 0.f};

  for (int k0 = 0; k0 < 512; k0 += 32) {
    bf16x8 a[4], bb[4];
#pragma unroll
    for (int mi = 0; mi < 4; ++mi)
      a[mi] = *reinterpret_cast<const bf16x8*>(
          vbf + (size_t)(m0 + wr * 64 + mi * 16 + lr) * 512 + k0 + lg * 8);
#pragma unroll
    for (int ni = 0; ni < 4; ++ni)
      bb[ni] = *reinterpret_cast<const bf16x8*>(
          w1t + (size_t)(n0 + wc * 64 + ni * 16 + lr) * 512 + k0 + lg * 8);
#pragma unroll
    for (int mi = 0; mi < 4; ++mi)
#pragma unroll
      for (int ni = 0; ni < 4; ++ni)
        acc[mi][ni] = __builtin_amdgcn_mfma_f32_16x16x32_bf16(a[mi], bb[ni], acc[mi][ni], 0, 0, 0);
  }
#pragma unroll
  for (int mi = 0; mi < 4; ++mi)
#pragma unroll
    for (int ni = 0; ni < 4; ++ni) {
      int col = n0 + wc * 64 + ni * 16 + lr;
      int h = col >> 7, j = col & 127;
      float bias = b1[col];
#pragma unroll
      for (int r = 0; r < 4; ++r) {
        int row = m0 + wr * 64 + mi * 16 + lg * 4 + r;
        int bb_ = row >> 10, s = row & 1023;
        unsigned short bv = f2bf(acc[mi][ni][r] + bias);
        size_t base = ((size_t)(bb_ * 16 + h) << 16) + (size_t)s * 64;
        if (j < 64) k_ws[base + j] = bv;
        else        q_ws[base + j - 64] = bv;
      }
    }
}

// ---------------- fused scores + softmax + attn write + PV ----------------
// grid (32 qt, 16 h, 8 b), 256 threads (4 waves). QBLK=32 rows shared by all waves;
// wave w owns a 64-col score slice per 256-chunk and 128 V-cols for PV.
// Softmax stats are wave-local online (no barriers), one cross-wave combine.
__launch_bounds__(256)
__global__ void attn_kernel(const unsigned short* __restrict__ q_ws,
                            const unsigned short* __restrict__ k_ws,
                            const unsigned short* __restrict__ vt,   // bf16 [512][8192]
                            const int* __restrict__ pad,             // [8][1024]
                            float* __restrict__ attn_out,            // [8][16][1024][1024]
                            unsigned short* __restrict__ o_ws) {     // bf16 [8][1024][8192]
  const int qt = blockIdx.x, h = blockIdx.y, b = blockIdx.z;
  const int bh = b * 16 + h, q0 = qt * 32;
  const int w = threadIdx.x >> 6, l = threadIdx.x & 63;
  const int lr = l & 15, lg = l >> 4;

  __shared__ unsigned short P_lds[32][264];  // stride 264 u16: b128 reads spread 8 bank-groups
  __shared__ float mw[4][32], lw[4][32];

  const unsigned short* qb = q_ws + ((size_t)bh << 16);
  const unsigned short* kb = k_ws + ((size_t)bh << 16);
  const int* pmb = pad + b * 1024;

  // Q fragments in registers for both passes
  bf16x8 a_q[2][2];
#pragma unroll
  for (int mf = 0; mf < 2; ++mf)
#pragma unroll
    for (int ks = 0; ks < 2; ++ks)
      a_q[mf][ks] = *reinterpret_cast<const bf16x8*>(
          qb + (size_t)(q0 + mf * 16 + lr) * 64 + ks * 32 + lg * 8);

  auto compute_s = [&](int kt, f32x4 (&s)[2][4]) {
    const int c0 = kt * 256 + w * 64;
#pragma unroll
    for (int mf = 0; mf < 2; ++mf)
#pragma unroll
      for (int nf = 0; nf < 4; ++nf) s[mf][nf] = (f32x4){0.f, 0.f, 0.f, 0.f};
#pragma unroll
    for (int ks = 0; ks < 2; ++ks) {
      bf16x8 bk[4];
#pragma unroll
      for (int nf = 0; nf < 4; ++nf)
        bk[nf] = *reinterpret_cast<const bf16x8*>(
            kb + (size_t)(c0 + nf * 16 + lr) * 64 + ks * 32 + lg * 8);
#pragma unroll
      for (int mf = 0; mf < 2; ++mf)
#pragma unroll
        for (int nf = 0; nf < 4; ++nf)
          s[mf][nf] = __builtin_amdgcn_mfma_f32_16x16x32_bf16(a_q[mf][ks], bk[nf], s[mf][nf], 0, 0, 0);
    }
    int msk[4];
#pragma unroll
    for (int nf = 0; nf < 4; ++nf) msk[nf] = pmb[c0 + nf * 16 + lr];
#pragma unroll
    for (int mf = 0; mf < 2; ++mf)
#pragma unroll
      for (int nf = 0; nf < 4; ++nf)
#pragma unroll
        for (int r = 0; r < 4; ++r)
          s[mf][nf][r] = msk[nf] ? -1000.f : s[mf][nf][r] * 0.125f;
  };

  // ---- pass A: wave-local online stats over this wave's col-slices ----
  float m_run[2][4], l_run[2][4];
#pragma unroll
  for (int mf = 0; mf < 2; ++mf)
#pragma unroll
    for (int r = 0; r < 4; ++r) { m_run[mf][r] = -1e30f; l_run[mf][r] = 0.f; }

  for (int kt = 0; kt < 4; ++kt) {
    f32x4 s[2][4];
    compute_s(kt, s);
#pragma unroll
    for (int mf = 0; mf < 2; ++mf)
#pragma unroll
      for (int r = 0; r < 4; ++r) {
        float cm = fmaxf(fmaxf(s[mf][0][r], s[mf][1][r]), fmaxf(s[mf][2][r], s[mf][3][r]));
#pragma unroll
        for (int off = 1; off < 16; off <<= 1) cm = fmaxf(cm, __shfl_xor(cm, off));
        float mn = fmaxf(m_run[mf][r], cm);
        float ex = 0.f;
#pragma unroll
        for (int nf = 0; nf < 4; ++nf) ex += __expf(s[mf][nf][r] - mn);
#pragma unroll
        for (int off = 1; off < 16; off <<= 1) ex += __shfl_xor(ex, off);
        l_run[mf][r] = l_run[mf][r] * __expf(m_run[mf][r] - mn) + ex;
        m_run[mf][r] = mn;
      }
  }

  // ---- cross-wave combine (single barrier) ----
  if (lr == 0) {
#pragma unroll
    for (int mf = 0; mf < 2; ++mf)
#pragma unroll
      for (int r = 0; r < 4; ++r) {
        int row = mf * 16 + lg * 4 + r;
        mw[w][row] = m_run[mf][r];
        lw[w][row] = l_run[mf][r];
      }
  }
  __syncthreads();
  float mloc[2][4], linv[2][4];
#pragma unroll
  for (int mf = 0; mf < 2; ++mf)
#pragma unroll
    for (int r = 0; r < 4; ++r) {
      int row = mf * 16 + lg * 4 + r;
      float m = fmaxf(fmaxf(mw[0][row], mw[1][row]), fmaxf(mw[2][row], mw[3][row]));
      float s = 0.f;
#pragma unroll
      for (int ww = 0; ww < 4; ++ww) s += lw[ww][row] * __expf(mw[ww][row] - m);
      mloc[mf][r] = m;
      linv[mf][r] = 1.f / s;
    }

  f32x4 acc_o[2][8];
#pragma unroll
  for (int mf = 0; mf < 2; ++mf)
#pragma unroll
    for (int nfo = 0; nfo < 8; ++nfo) acc_o[mf][nfo] = (f32x4){0.f, 0.f, 0.f, 0.f};

  float* attn_b = attn_out + ((size_t)bh << 20) + (size_t)q0 * 1024;
  const unsigned short* vtb = vt + (size_t)b * 1024;

  // ---- pass B: recompute scores, write attn, PV-accumulate ----
  for (int kt = 0; kt < 4; ++kt) {
    f32x4 s[2][4];
    compute_s(kt, s);
    const int c0 = kt * 256 + w * 64;
#pragma unroll
    for (int mf = 0; mf < 2; ++mf)
#pragma unroll
      for (int nf = 0; nf < 4; ++nf)
#pragma unroll
        for (int r = 0; r < 4; ++r) {
          int row = mf * 16 + lg * 4 + r;
          int col = c0 + nf * 16 + lr;
          float p = __expf(s[mf][nf][r] - mloc[mf][r]) * linv[mf][r];
          attn_b[(size_t)row * 1024 + col] = p;
          P_lds[row][w * 64 + nf * 16 + lr] = f2bf(p);
        }
    __syncthreads();
#pragma unroll
    for (int ks = 0; ks < 8; ++ks) {
      bf16x8 pa[2];
#pragma unroll
      for (int mf = 0; mf < 2; ++mf)
        pa[mf] = *reinterpret_cast<const bf16x8*>(&P_lds[mf * 16 + lr][ks * 32 + lg * 8]);
#pragma unroll
      for (int nfo = 0; nfo < 8; ++nfo) {
        bf16x8 bv = *reinterpret_cast<const bf16x8*>(
            vtb + (size_t)(w * 128 + nfo * 16 + lr) * 8192 + kt * 256 + ks * 32 + lg * 8);
#pragma unroll
        for (int mf = 0; mf < 2; ++mf)
          acc_o[mf][nfo] = __builtin_amdgcn_mfma_f32_16x16x32_bf16(pa[mf], bv, acc_o[mf][nfo], 0, 0, 0);
      }
    }
    __syncthreads();
  }

  // write O tile (bf16) to o_ws [b][s][h*512+c]
#pragma unroll
  for (int mf = 0; mf < 2; ++mf)
#pragma unroll
    for (int nfo = 0; nfo < 8; ++nfo)
#pragma unroll
      for (int r = 0; r < 4; ++r) {
        int row = q0 + mf * 16 + lg * 4 + r;
        int col = w * 128 + nfo * 16 + lr;
        o_ws[(size_t)(b * 1024 + row) * 8192 + h * 512 + col] = f2bf(acc_o[mf][nfo][r]);
      }
}

// ---------------- GEMM2: y = o @ W2 + b2  (m97 structure: 128^2 tile, BK=32) ----------------
__launch_bounds__(256)
__global__ void gemm2_kernel(const unsigned short* __restrict__ o_ws,
                             const unsigned short* __restrict__ w2t,
                             const float* __restrict__ b2,
                             float* __restrict__ y) {
  __shared__ unsigned short Asm[128 * 32];
  __shared__ unsigned short Bsm[128 * 32];
  const int m0 = blockIdx.y * 128, n0 = blockIdx.x * 128;
  const int w = threadIdx.x >> 6, l = threadIdx.x & 63;
  const int wr = w >> 1, wc = w & 1, lr = l & 15, lg = l >> 4;

  f32x4 acc[4][4];
#pragma unroll
  for (int mi = 0; mi < 4; ++mi)
#pragma unroll
    for (int ni = 0; ni < 4; ++ni) acc[mi][ni] = (f32x4){0.f, 0.f, 0.f, 0.f};

  const int srow = l >> 2;          // 0..15
  const int scol = (l & 3) * 8;     // 0,8,16,24
  const unsigned short* gA = o_ws + (size_t)(m0 + w * 32 + srow) * 8192 + scol;
  const unsigned short* gB = w2t + (size_t)(n0 + w * 32 + srow) * 8192 + scol;
  unsigned short* lA = Asm + (w * 32) * 32;   // wave-uniform LDS base
  unsigned short* lB = Bsm + (w * 32) * 32;

  for (int k0 = 0; k0 < 8192; k0 += 32) {
    gload_lds16(gA + k0, lA);
    gload_lds16(gA + (size_t)16 * 8192 + k0, lA + 16 * 32);
    gload_lds16(gB + k0, lB);
    gload_lds16(gB + (size_t)16 * 8192 + k0, lB + 16 * 32);
    __syncthreads();
    bf16x8 a[4], bb[4];
#pragma unroll
    for (int mi = 0; mi < 4; ++mi)
      a[mi] = *reinterpret_cast<const bf16x8*>(Asm + (wr * 64 + mi * 16 + lr) * 32 + lg * 8);
#pragma unroll
    for (int ni = 0; ni < 4; ++ni)
      bb[ni] = *reinterpret_cast<const bf16x8*>(Bsm + (wc * 64 + ni * 16 + lr) * 32 + lg * 8);
#pragma unroll
    for (int mi = 0; mi < 4; ++mi)
#pragma unroll
      for (int ni = 0; ni < 4; ++ni)
        acc[mi][ni] = __builtin_amdgcn_mfma_f32_16x16x32_bf16(a[mi], bb[ni], acc[mi][ni], 0, 0, 0);
    __syncthreads();
  }

#pragma unroll
  for (int mi = 0; mi < 4; ++mi)
#pragma unroll
    for (int ni = 0; ni < 4; ++ni) {
      int col = n0 + wc * 64 + ni * 16 + lr;
      float bias = b2[col];
#pragma unroll
      for (int r = 0; r < 4; ++r)
        y[(size_t)(m0 + wr * 64 + mi * 16 + lg * 4 + r) * 512 + col] = acc[mi][ni][r] + bias;
    }
}

// ---------------- launch ----------------
extern "C" void kernel_launch(void* const* d_in, const int* in_sizes, int n_in,
                              void* d_out, int out_size, void* d_ws, size_t ws_size,
                              hipStream_t stream) {
  const float* v   = (const float*)d_in[0];
  const int*   pad = (const int*)d_in[1];
  const float* W1  = (const float*)d_in[2];
  const float* b1  = (const float*)d_in[3];
  const float* W2  = (const float*)d_in[4];
  const float* b2  = (const float*)d_in[5];
  float* out  = (float*)d_out;
  float* attn = out + (size_t)8 * 1024 * 512;

  char* ws = (char*)d_ws;
  unsigned short* w1t  = (unsigned short*)(ws);              //  2 MB  [2048][512]
  unsigned short* w2t  = (unsigned short*)(ws + 2097152);    //  8 MB  [512][8192]
  unsigned short* vt   = (unsigned short*)(ws + 10485760);   //  8 MB  [512][8192]
  unsigned short* vbf  = (unsigned short*)(ws + 18874368);   //  8 MB  [8192][512]
  unsigned short* q_ws = (unsigned short*)(ws + 27262976);   // 16 MB  [128][1024][64]
  unsigned short* k_ws = (unsigned short*)(ws + 44040192);   // 16 MB  [128][1024][64]
  unsigned short* o_ws = (unsigned short*)(ws + 60817408);   // 134 MB [8192][8192]

  transpose_cvt_kernel<<<dim3(64, 16), 256, 0, stream>>>(W1, w1t, 512, 2048);
  transpose_cvt_kernel<<<dim3(16, 256), 256, 0, stream>>>(W2, w2t, 8192, 512);
  transpose_cvt_kernel<<<dim3(16, 256), 256, 0, stream>>>(v, vt, 8192, 512);
  cvt_bf16_kernel<<<4096, 256, 0, stream>>>(v, vbf, 1048576);
  gemm1_kernel<<<dim3(16, 64), 256, 0, stream>>>(vbf, w1t, b1, q_ws, k_ws);
  attn_kernel<<<dim3(32, 16, 8), 256, 0, stream>>>(q_ws, k_ws, vt, pad, attn, o_ws);
  gemm2_kernel<<<dim3(4, 64), 256, 0, stream>>>(o_ws, w2t, b2, out);  // 64*128 = 8192 rows (R2 bug: was 128)
}

// Round 4
// 962.066 us; speedup vs baseline: 1.3167x; 1.3167x over previous
//
#include <hip/hip_runtime.h>

// MultiHeadAttention: v(8,1024,512) fp32, pad(8,1,1,1024) int, W1(512,2048), b1(2048),
// W2(8192,512), b2(512) -> out (8,1024,512) fp32 ++ attn (8,16,1024,1024) fp32.
// All matmuls in bf16 MFMA 16x16x32, fp32 accumulate.

typedef __attribute__((ext_vector_type(8))) short bf16x8;
typedef __attribute__((ext_vector_type(4))) float f32x4;
typedef __attribute__((ext_vector_type(4))) unsigned short u16x4;

__device__ __forceinline__ unsigned short f2bf(float f) {
  unsigned u = __builtin_bit_cast(unsigned, f);
  u += 0x7FFFu + ((u >> 16) & 1u);   // RTN-even
  return (unsigned short)(u >> 16);
}
__device__ __forceinline__ float bf2f(unsigned short u) {
  return __builtin_bit_cast(float, (unsigned)u << 16);
}

__device__ __forceinline__ void gload_lds16(const unsigned short* g, unsigned short* l) {
  __builtin_amdgcn_global_load_lds(
      (const __attribute__((address_space(1))) unsigned int*)(g),
      (__attribute__((address_space(3))) unsigned int*)(l), 16, 0, 0);
}

// ---------------- preprocessing ----------------

__global__ void cvt_bf16_kernel(const float* __restrict__ in,
                                unsigned short* __restrict__ out, int n4) {
  int i = blockIdx.x * blockDim.x + threadIdx.x;
  if (i >= n4) return;
  f32x4 v = reinterpret_cast<const f32x4*>(in)[i];
  u16x4 o;
#pragma unroll
  for (int j = 0; j < 4; ++j) o[j] = f2bf(v[j]);
  reinterpret_cast<u16x4*>(out)[i] = o;
}

// in fp32 [R][C] -> out bf16 [C][R]
__global__ void transpose_cvt_kernel(const float* __restrict__ in,
                                     unsigned short* __restrict__ out,
                                     int R, int C) {
  __shared__ float tile[32][33];
  int c0 = blockIdx.x * 32, r0 = blockIdx.y * 32;
  int tx = threadIdx.x & 31, ty = threadIdx.x >> 5;
#pragma unroll
  for (int i = ty; i < 32; i += 8)
    tile[i][tx] = in[(size_t)(r0 + i) * C + (c0 + tx)];
  __syncthreads();
#pragma unroll
  for (int i = ty; i < 32; i += 8)
    out[(size_t)(c0 + i) * R + (r0 + tx)] = f2bf(tile[tx][i]);
}

// ---------------- GEMM1: kq = v @ W1 + b1 ----------------
__launch_bounds__(256)
__global__ void gemm1_kernel(const unsigned short* __restrict__ vbf,
                             const unsigned short* __restrict__ w1t,
                             const float* __restrict__ b1,
                             unsigned short* __restrict__ q_ws,
                             unsigned short* __restrict__ k_ws) {
  const int m0 = blockIdx.y * 128, n0 = blockIdx.x * 128;
  const int w = threadIdx.x >> 6, l = threadIdx.x & 63;
  const int wr = w >> 1, wc = w & 1, lr = l & 15, lg = l >> 4;
  f32x4 acc[4][4];
#pragma unroll
  for (int mi = 0; mi < 4; ++mi)
#pragma unroll
    for (int ni = 0; ni < 4; ++ni) acc[mi][ni] = (f32x4){0.f, 0.f, 0.f, 0.f};

  for (int k0 = 0; k0 < 512; k0 += 32) {
    bf16x8 a[4], bb[4];
#pragma unroll
    for (int mi = 0; mi < 4; ++mi)
      a[mi] = *reinterpret_cast<const bf16x8*>(
          vbf + (size_t)(m0 + wr * 64 + mi * 16 + lr) * 512 + k0 + lg * 8);
#pragma unroll
    for (int ni = 0; ni < 4; ++ni)
      bb[ni] = *reinterpret_cast<const bf16x8*>(
          w1t + (size_t)(n0 + wc * 64 + ni * 16 + lr) * 512 + k0 + lg * 8);
#pragma unroll
    for (int mi = 0; mi < 4; ++mi)
#pragma unroll
      for (int ni = 0; ni < 4; ++ni)
        acc[mi][ni] = __builtin_amdgcn_mfma_f32_16x16x32_bf16(a[mi], bb[ni], acc[mi][ni], 0, 0, 0);
  }
#pragma unroll
  for (int mi = 0; mi < 4; ++mi)
#pragma unroll
    for (int ni = 0; ni < 4; ++ni) {
      int col = n0 + wc * 64 + ni * 16 + lr;
      int h = col >> 7, j = col & 127;
      float bias = b1[col];
#pragma unroll
      for (int r = 0; r < 4; ++r) {
        int row = m0 + wr * 64 + mi * 16 + lg * 4 + r;
        int bb_ = row >> 10, s = row & 1023;
        unsigned short bv = f2bf(acc[mi][ni][r] + bias);
        size_t base = ((size_t)(bb_ * 16 + h) << 16) + (size_t)s * 64;
        if (j < 64) k_ws[base + j] = bv;
        else        q_ws[base + j - 64] = bv;
      }
    }
}

// ---------------- fused attn: single-pass scores -> exp (no max-sub) -> attn write + PV ----------------
// grid (32 qt, 16 h, 8 b), 512 threads (8 waves). QBLK=32 rows.
// Phase 1: wave w computes exp(scores) for cols w*128..+127 into E_lds, row-sums l.
// Phase 2: attn = E * (1/l), wide f32x4 stores. Phase 3: O = (E @ V) * (1/l).
__launch_bounds__(512, 4)
__global__ void attn_kernel(const unsigned short* __restrict__ q_ws,
                            const unsigned short* __restrict__ k_ws,
                            const unsigned short* __restrict__ vt,   // bf16 [512][8192]
                            const int* __restrict__ pad,             // [8][1024]
                            float* __restrict__ attn_out,            // [8][16][1024][1024]
                            unsigned short* __restrict__ o_ws) {     // bf16 [8][1024][8192]
  const int qt = blockIdx.x, h = blockIdx.y, b = blockIdx.z;
  const int bh = b * 16 + h, q0 = qt * 32;
  const int w = threadIdx.x >> 6, l = threadIdx.x & 63;
  const int lr = l & 15, lg = l >> 4;

  __shared__ unsigned short E_lds[32][1040];  // stride 2080B == 8 dwords mod 32: even bank spread
  __shared__ float lw[8][32];
  __shared__ float linv_s[32];

  const unsigned short* qb = q_ws + ((size_t)bh << 16);
  const unsigned short* kb = k_ws + ((size_t)bh << 16);
  const int* pmb = pad + b * 1024;

  // Q fragments in registers
  bf16x8 a_q[2][2];
#pragma unroll
  for (int mf = 0; mf < 2; ++mf)
#pragma unroll
    for (int ks = 0; ks < 2; ++ks)
      a_q[mf][ks] = *reinterpret_cast<const bf16x8*>(
          qb + (size_t)(q0 + mf * 16 + lr) * 64 + ks * 32 + lg * 8);

  // ---- phase 1: scores -> exp -> E_lds + per-lane partial row sums ----
  float l_run[2][4];
#pragma unroll
  for (int mf = 0; mf < 2; ++mf)
#pragma unroll
    for (int r = 0; r < 4; ++r) l_run[mf][r] = 0.f;

#pragma unroll
  for (int sub = 0; sub < 2; ++sub) {
    const int c0 = w * 128 + sub * 64;
    f32x4 s[2][4];
#pragma unroll
    for (int mf = 0; mf < 2; ++mf)
#pragma unroll
      for (int nf = 0; nf < 4; ++nf) s[mf][nf] = (f32x4){0.f, 0.f, 0.f, 0.f};
#pragma unroll
    for (int ks = 0; ks < 2; ++ks) {
      bf16x8 bk[4];
#pragma unroll
      for (int nf = 0; nf < 4; ++nf)
        bk[nf] = *reinterpret_cast<const bf16x8*>(
            kb + (size_t)(c0 + nf * 16 + lr) * 64 + ks * 32 + lg * 8);
#pragma unroll
      for (int mf = 0; mf < 2; ++mf)
#pragma unroll
        for (int nf = 0; nf < 4; ++nf)
          s[mf][nf] = __builtin_amdgcn_mfma_f32_16x16x32_bf16(a_q[mf][ks], bk[nf], s[mf][nf], 0, 0, 0);
    }
    int msk[4];
#pragma unroll
    for (int nf = 0; nf < 4; ++nf) msk[nf] = pmb[c0 + nf * 16 + lr];
#pragma unroll
    for (int mf = 0; mf < 2; ++mf)
#pragma unroll
      for (int nf = 0; nf < 4; ++nf)
#pragma unroll
        for (int r = 0; r < 4; ++r) {
          float e = msk[nf] ? 0.f : __expf(s[mf][nf][r] * 0.125f);
          l_run[mf][r] += e;
          E_lds[mf * 16 + lg * 4 + r][c0 + nf * 16 + lr] = f2bf(e);
        }
  }
  // reduce row sums over the 16 lr lanes
#pragma unroll
  for (int mf = 0; mf < 2; ++mf)
#pragma unroll
    for (int r = 0; r < 4; ++r) {
      float v = l_run[mf][r];
      v += __shfl_xor(v, 1); v += __shfl_xor(v, 2);
      v += __shfl_xor(v, 4); v += __shfl_xor(v, 8);
      if (lr == 0) lw[w][mf * 16 + lg * 4 + r] = v;
    }
  __syncthreads();
  if (threadIdx.x < 32) {
    float s = 0.f;
#pragma unroll
    for (int ww = 0; ww < 8; ++ww) s += lw[ww][threadIdx.x];
    linv_s[threadIdx.x] = 1.f / s;
  }
  __syncthreads();

  // ---- phase 2: write normalized attn with wide stores ----
  {
    float* attn_b = attn_out + ((size_t)bh << 20) + (size_t)q0 * 1024;
    const int row = threadIdx.x >> 4;        // 32 rows, 16 threads/row
    const int cb = threadIdx.x & 15;
    const float sc = linv_s[row];
    float* rowp = attn_b + (size_t)row * 1024;
#pragma unroll
    for (int i = 0; i < 8; ++i) {
      int c8 = (cb + i * 16) * 8;
      bf16x8 ev = *reinterpret_cast<const bf16x8*>(&E_lds[row][c8]);
      f32x4 o0, o1;
#pragma unroll
      for (int j = 0; j < 4; ++j) o0[j] = bf2f((unsigned short)ev[j]) * sc;
#pragma unroll
      for (int j = 0; j < 4; ++j) o1[j] = bf2f((unsigned short)ev[4 + j]) * sc;
      *reinterpret_cast<f32x4*>(rowp + c8) = o0;
      *reinterpret_cast<f32x4*>(rowp + c8 + 4) = o1;
    }
  }

  // ---- phase 3: PV from E_lds, scale by linv at the end ----
  f32x4 acc[2][4];
#pragma unroll
  for (int mf = 0; mf < 2; ++mf)
#pragma unroll
    for (int nfo = 0; nfo < 4; ++nfo) acc[mf][nfo] = (f32x4){0.f, 0.f, 0.f, 0.f};

  const unsigned short* vtb = vt + (size_t)b * 1024;
  for (int ks = 0; ks < 32; ++ks) {
    bf16x8 pa[2];
#pragma unroll
    for (int mf = 0; mf < 2; ++mf)
      pa[mf] = *reinterpret_cast<const bf16x8*>(&E_lds[mf * 16 + lr][ks * 32 + lg * 8]);
#pragma unroll
    for (int nfo = 0; nfo < 4; ++nfo) {
      bf16x8 bv = *reinterpret_cast<const bf16x8*>(
          vtb + (size_t)(w * 64 + nfo * 16 + lr) * 8192 + ks * 32 + lg * 8);
#pragma unroll
      for (int mf = 0; mf < 2; ++mf)
        acc[mf][nfo] = __builtin_amdgcn_mfma_f32_16x16x32_bf16(pa[mf], bv, acc[mf][nfo], 0, 0, 0);
    }
  }

#pragma unroll
  for (int mf = 0; mf < 2; ++mf)
#pragma unroll
    for (int nfo = 0; nfo < 4; ++nfo)
#pragma unroll
      for (int r = 0; r < 4; ++r) {
        int row = mf * 16 + lg * 4 + r;
        float val = acc[mf][nfo][r] * linv_s[row];
        o_ws[(size_t)(b * 1024 + q0 + row) * 8192 + h * 512 + w * 64 + nfo * 16 + lr] = f2bf(val);
      }
}

// ---------------- GEMM2: y = o @ W2 + b2  (m97 structure: 128^2 tile, BK=32) ----------------
__launch_bounds__(256)
__global__ void gemm2_kernel(const unsigned short* __restrict__ o_ws,
                             const unsigned short* __restrict__ w2t,
                             const float* __restrict__ b2,
                             float* __restrict__ y) {
  __shared__ unsigned short Asm[128 * 32];
  __shared__ unsigned short Bsm[128 * 32];
  const int m0 = blockIdx.y * 128, n0 = blockIdx.x * 128;
  const int w = threadIdx.x >> 6, l = threadIdx.x & 63;
  const int wr = w >> 1, wc = w & 1, lr = l & 15, lg = l >> 4;

  f32x4 acc[4][4];
#pragma unroll
  for (int mi = 0; mi < 4; ++mi)
#pragma unroll
    for (int ni = 0; ni < 4; ++ni) acc[mi][ni] = (f32x4){0.f, 0.f, 0.f, 0.f};

  const int srow = l >> 2;          // 0..15
  const int scol = (l & 3) * 8;     // 0,8,16,24
  const unsigned short* gA = o_ws + (size_t)(m0 + w * 32 + srow) * 8192 + scol;
  const unsigned short* gB = w2t + (size_t)(n0 + w * 32 + srow) * 8192 + scol;
  unsigned short* lA = Asm + (w * 32) * 32;   // wave-uniform LDS base
  unsigned short* lB = Bsm + (w * 32) * 32;

  for (int k0 = 0; k0 < 8192; k0 += 32) {
    gload_lds16(gA + k0, lA);
    gload_lds16(gA + (size_t)16 * 8192 + k0, lA + 16 * 32);
    gload_lds16(gB + k0, lB);
    gload_lds16(gB + (size_t)16 * 8192 + k0, lB + 16 * 32);
    __syncthreads();
    bf16x8 a[4], bb[4];
#pragma unroll
    for (int mi = 0; mi < 4; ++mi)
      a[mi] = *reinterpret_cast<const bf16x8*>(Asm + (wr * 64 + mi * 16 + lr) * 32 + lg * 8);
#pragma unroll
    for (int ni = 0; ni < 4; ++ni)
      bb[ni] = *reinterpret_cast<const bf16x8*>(Bsm + (wc * 64 + ni * 16 + lr) * 32 + lg * 8);
#pragma unroll
    for (int mi = 0; mi < 4; ++mi)
#pragma unroll
      for (int ni = 0; ni < 4; ++ni)
        acc[mi][ni] = __builtin_amdgcn_mfma_f32_16x16x32_bf16(a[mi], bb[ni], acc[mi][ni], 0, 0, 0);
    __syncthreads();
  }

#pragma unroll
  for (int mi = 0; mi < 4; ++mi)
#pragma unroll
    for (int ni = 0; ni < 4; ++ni) {
      int col = n0 + wc * 64 + ni * 16 + lr;
      float bias = b2[col];
#pragma unroll
      for (int r = 0; r < 4; ++r)
        y[(size_t)(m0 + wr * 64 + mi * 16 + lg * 4 + r) * 512 + col] = acc[mi][ni][r] + bias;
    }
}

// ---------------- launch ----------------
extern "C" void kernel_launch(void* const* d_in, const int* in_sizes, int n_in,
                              void* d_out, int out_size, void* d_ws, size_t ws_size,
                              hipStream_t stream) {
  const float* v   = (const float*)d_in[0];
  const int*   pad = (const int*)d_in[1];
  const float* W1  = (const float*)d_in[2];
  const float* b1  = (const float*)d_in[3];
  const float* W2  = (const float*)d_in[4];
  const float* b2  = (const float*)d_in[5];
  float* out  = (float*)d_out;
  float* attn = out + (size_t)8 * 1024 * 512;

  char* ws = (char*)d_ws;
  unsigned short* w1t  = (unsigned short*)(ws);              //  2 MB  [2048][512]
  unsigned short* w2t  = (unsigned short*)(ws + 2097152);    //  8 MB  [512][8192]
  unsigned short* vt   = (unsigned short*)(ws + 10485760);   //  8 MB  [512][8192]
  unsigned short* vbf  = (unsigned short*)(ws + 18874368);   //  8 MB  [8192][512]
  unsigned short* q_ws = (unsigned short*)(ws + 27262976);   // 16 MB  [128][1024][64]
  unsigned short* k_ws = (unsigned short*)(ws + 44040192);   // 16 MB  [128][1024][64]
  unsigned short* o_ws = (unsigned short*)(ws + 60817408);   // 134 MB [8192][8192]

  transpose_cvt_kernel<<<dim3(64, 16), 256, 0, stream>>>(W1, w1t, 512, 2048);
  transpose_cvt_kernel<<<dim3(16, 256), 256, 0, stream>>>(W2, w2t, 8192, 512);
  transpose_cvt_kernel<<<dim3(16, 256), 256, 0, stream>>>(v, vt, 8192, 512);
  cvt_bf16_kernel<<<4096, 256, 0, stream>>>(v, vbf, 1048576);
  gemm1_kernel<<<dim3(16, 64), 256, 0, stream>>>(vbf, w1t, b1, q_ws, k_ws);
  attn_kernel<<<dim3(32, 16, 8), 512, 0, stream>>>(q_ws, k_ws, vt, pad, attn, o_ws);
  gemm2_kernel<<<dim3(4, 64), 256, 0, stream>>>(o_ws, w2t, b2, out);
}

// Round 5
// 857.075 us; speedup vs baseline: 1.4780x; 1.1225x over previous
//
#include <hip/hip_runtime.h>

// MultiHeadAttention: v(8,1024,512) fp32, pad(8,1,1,1024) int, W1(512,2048), b1(2048),
// W2(8192,512), b2(512) -> out (8,1024,512) fp32 ++ attn (8,16,1024,1024) fp32.
// All matmuls in bf16 MFMA 16x16x32, fp32 accumulate.

typedef __attribute__((ext_vector_type(8))) short bf16x8;
typedef __attribute__((ext_vector_type(4))) float f32x4;
typedef __attribute__((ext_vector_type(4))) unsigned short u16x4;

__device__ __forceinline__ unsigned short f2bf(float f) {
  unsigned u = __builtin_bit_cast(unsigned, f);
  u += 0x7FFFu + ((u >> 16) & 1u);   // RTN-even
  return (unsigned short)(u >> 16);
}
__device__ __forceinline__ float bf2f(unsigned short u) {
  return __builtin_bit_cast(float, (unsigned)u << 16);
}

__device__ __forceinline__ void gload_lds16(const unsigned short* g, unsigned short* l) {
  __builtin_amdgcn_global_load_lds(
      (const __attribute__((address_space(1))) unsigned int*)(g),
      (__attribute__((address_space(3))) unsigned int*)(l), 16, 0, 0);
}

// ---------------- preprocessing ----------------

__global__ void cvt_bf16_kernel(const float* __restrict__ in,
                                unsigned short* __restrict__ out, int n4) {
  int i = blockIdx.x * blockDim.x + threadIdx.x;
  if (i >= n4) return;
  f32x4 v = reinterpret_cast<const f32x4*>(in)[i];
  u16x4 o;
#pragma unroll
  for (int j = 0; j < 4; ++j) o[j] = f2bf(v[j]);
  reinterpret_cast<u16x4*>(out)[i] = o;
}

// in fp32 [R][C] -> out bf16 [C][R]
__global__ void transpose_cvt_kernel(const float* __restrict__ in,
                                     unsigned short* __restrict__ out,
                                     int R, int C) {
  __shared__ float tile[32][33];
  int c0 = blockIdx.x * 32, r0 = blockIdx.y * 32;
  int tx = threadIdx.x & 31, ty = threadIdx.x >> 5;
#pragma unroll
  for (int i = ty; i < 32; i += 8)
    tile[i][tx] = in[(size_t)(r0 + i) * C + (c0 + tx)];
  __syncthreads();
#pragma unroll
  for (int i = ty; i < 32; i += 8)
    out[(size_t)(c0 + i) * R + (r0 + tx)] = f2bf(tile[tx][i]);
}

// ---------------- GEMM1: kq = v @ W1 + b1 ----------------
__launch_bounds__(256)
__global__ void gemm1_kernel(const unsigned short* __restrict__ vbf,
                             const unsigned short* __restrict__ w1t,
                             const float* __restrict__ b1,
                             unsigned short* __restrict__ q_ws,
                             unsigned short* __restrict__ k_ws) {
  const int m0 = blockIdx.y * 128, n0 = blockIdx.x * 128;
  const int w = threadIdx.x >> 6, l = threadIdx.x & 63;
  const int wr = w >> 1, wc = w & 1, lr = l & 15, lg = l >> 4;
  f32x4 acc[4][4];
#pragma unroll
  for (int mi = 0; mi < 4; ++mi)
#pragma unroll
    for (int ni = 0; ni < 4; ++ni) acc[mi][ni] = (f32x4){0.f, 0.f, 0.f, 0.f};

  for (int k0 = 0; k0 < 512; k0 += 32) {
    bf16x8 a[4], bb[4];
#pragma unroll
    for (int mi = 0; mi < 4; ++mi)
      a[mi] = *reinterpret_cast<const bf16x8*>(
          vbf + (size_t)(m0 + wr * 64 + mi * 16 + lr) * 512 + k0 + lg * 8);
#pragma unroll
    for (int ni = 0; ni < 4; ++ni)
      bb[ni] = *reinterpret_cast<const bf16x8*>(
          w1t + (size_t)(n0 + wc * 64 + ni * 16 + lr) * 512 + k0 + lg * 8);
#pragma unroll
    for (int mi = 0; mi < 4; ++mi)
#pragma unroll
      for (int ni = 0; ni < 4; ++ni)
        acc[mi][ni] = __builtin_amdgcn_mfma_f32_16x16x32_bf16(a[mi], bb[ni], acc[mi][ni], 0, 0, 0);
  }
#pragma unroll
  for (int mi = 0; mi < 4; ++mi)
#pragma unroll
    for (int ni = 0; ni < 4; ++ni) {
      int col = n0 + wc * 64 + ni * 16 + lr;
      int h = col >> 7, j = col & 127;
      float bias = b1[col];
#pragma unroll
      for (int r = 0; r < 4; ++r) {
        int row = m0 + wr * 64 + mi * 16 + lg * 4 + r;
        int bb_ = row >> 10, s = row & 1023;
        unsigned short bv = f2bf(acc[mi][ni][r] + bias);
        size_t base = ((size_t)(bb_ * 16 + h) << 16) + (size_t)s * 64;
        if (j < 64) k_ws[base + j] = bv;
        else        q_ws[base + j - 64] = bv;
      }
    }
}

// ---------------- fused attn: single-pass scores -> exp -> attn write + PV ----------------
// 4096 blocks (XCD-swizzled), 512 threads (8 waves). QBLK=32 rows.
__launch_bounds__(512, 4)
__global__ void attn_kernel(const unsigned short* __restrict__ q_ws,
                            const unsigned short* __restrict__ k_ws,
                            const unsigned short* __restrict__ vt,   // bf16 [512][8192]
                            const int* __restrict__ pad,             // [8][1024]
                            float* __restrict__ attn_out,            // [8][16][1024][1024]
                            unsigned short* __restrict__ o_ws) {     // bf16 [8][1024][8192]
  // XCD-aware swizzle: 4096 % 8 == 0 -> bijective; XCD x handles wg x*512..x*512+511
  const int wg = (blockIdx.x & 7) * 512 + (blockIdx.x >> 3);
  const int qt = wg & 31, h = (wg >> 5) & 15, b = wg >> 9;
  const int bh = b * 16 + h, q0 = qt * 32;
  const int w = threadIdx.x >> 6, l = threadIdx.x & 63;
  const int lr = l & 15, lg = l >> 4;

  __shared__ unsigned short E_lds[32][1048];  // 524 dwords/row === 12 mod 32 -> 2-way max on b128 reads
  __shared__ float lw[8][32];
  __shared__ float linv_s[32];

  const unsigned short* qb = q_ws + ((size_t)bh << 16);
  const unsigned short* kb = k_ws + ((size_t)bh << 16);
  const int* pmb = pad + b * 1024;

  // Q fragments in registers
  bf16x8 a_q[2][2];
#pragma unroll
  for (int mf = 0; mf < 2; ++mf)
#pragma unroll
    for (int ks = 0; ks < 2; ++ks)
      a_q[mf][ks] = *reinterpret_cast<const bf16x8*>(
          qb + (size_t)(q0 + mf * 16 + lr) * 64 + ks * 32 + lg * 8);

  // ---- phase 1: scores -> exp -> E_lds + per-lane partial row sums ----
  float l_run[2][4];
#pragma unroll
  for (int mf = 0; mf < 2; ++mf)
#pragma unroll
    for (int r = 0; r < 4; ++r) l_run[mf][r] = 0.f;

  // K-fragment base: row = w*128 + sub*64 + nf*16 + lr, col = ks*32 + lg*8
  const unsigned short* kwb = kb + (size_t)(w * 128 + lr) * 64 + lg * 8;

  bf16x8 bkA[2][4], bkB[2][4];   // [ks][nf], sub0 / sub1
#pragma unroll
  for (int ks = 0; ks < 2; ++ks)
#pragma unroll
    for (int nf = 0; nf < 4; ++nf)
      bkA[ks][nf] = *reinterpret_cast<const bf16x8*>(kwb + (size_t)(nf * 16) * 64 + ks * 32);

  f32x4 s0[2][4], s1[2][4];
#pragma unroll
  for (int mf = 0; mf < 2; ++mf)
#pragma unroll
    for (int nf = 0; nf < 4; ++nf) { s0[mf][nf] = (f32x4){0.f,0.f,0.f,0.f}; s1[mf][nf] = (f32x4){0.f,0.f,0.f,0.f}; }

#pragma unroll
  for (int ks = 0; ks < 2; ++ks)
#pragma unroll
    for (int mf = 0; mf < 2; ++mf)
#pragma unroll
      for (int nf = 0; nf < 4; ++nf)
        s0[mf][nf] = __builtin_amdgcn_mfma_f32_16x16x32_bf16(a_q[mf][ks], bkA[ks][nf], s0[mf][nf], 0, 0, 0);

  // issue sub1 K-loads early (overlap with sub0 exp/store)
#pragma unroll
  for (int ks = 0; ks < 2; ++ks)
#pragma unroll
    for (int nf = 0; nf < 4; ++nf)
      bkB[ks][nf] = *reinterpret_cast<const bf16x8*>(kwb + (size_t)(64 + nf * 16) * 64 + ks * 32);

  {
    const int c0 = w * 128;
    int msk[4];
#pragma unroll
    for (int nf = 0; nf < 4; ++nf) msk[nf] = pmb[c0 + nf * 16 + lr];
#pragma unroll
    for (int mf = 0; mf < 2; ++mf)
#pragma unroll
      for (int nf = 0; nf < 4; ++nf)
#pragma unroll
        for (int r = 0; r < 4; ++r) {
          float e = msk[nf] ? 0.f : __expf(s0[mf][nf][r] * 0.125f);
          l_run[mf][r] += e;
          E_lds[mf * 16 + lg * 4 + r][c0 + nf * 16 + lr] = f2bf(e);
        }
  }

#pragma unroll
  for (int ks = 0; ks < 2; ++ks)
#pragma unroll
    for (int mf = 0; mf < 2; ++mf)
#pragma unroll
      for (int nf = 0; nf < 4; ++nf)
        s1[mf][nf] = __builtin_amdgcn_mfma_f32_16x16x32_bf16(a_q[mf][ks], bkB[ks][nf], s1[mf][nf], 0, 0, 0);

  {
    const int c0 = w * 128 + 64;
    int msk[4];
#pragma unroll
    for (int nf = 0; nf < 4; ++nf) msk[nf] = pmb[c0 + nf * 16 + lr];
#pragma unroll
    for (int mf = 0; mf < 2; ++mf)
#pragma unroll
      for (int nf = 0; nf < 4; ++nf)
#pragma unroll
        for (int r = 0; r < 4; ++r) {
          float e = msk[nf] ? 0.f : __expf(s1[mf][nf][r] * 0.125f);
          l_run[mf][r] += e;
          E_lds[mf * 16 + lg * 4 + r][c0 + nf * 16 + lr] = f2bf(e);
        }
  }

  // reduce row sums over the 16 lr lanes
#pragma unroll
  for (int mf = 0; mf < 2; ++mf)
#pragma unroll
    for (int r = 0; r < 4; ++r) {
      float v = l_run[mf][r];
      v += __shfl_xor(v, 1); v += __shfl_xor(v, 2);
      v += __shfl_xor(v, 4); v += __shfl_xor(v, 8);
      if (lr == 0) lw[w][mf * 16 + lg * 4 + r] = v;
    }
  __syncthreads();
  if (threadIdx.x < 32) {
    float s = 0.f;
#pragma unroll
    for (int ww = 0; ww < 8; ++ww) s += lw[ww][threadIdx.x];
    linv_s[threadIdx.x] = 1.f / s;
  }
  __syncthreads();

  // ---- phase 2: write normalized attn with wide stores ----
  {
    float* attn_b = attn_out + ((size_t)bh << 20) + (size_t)q0 * 1024;
    const int row = threadIdx.x >> 4;        // 32 rows, 16 threads/row
    const int cb = threadIdx.x & 15;
    const float sc = linv_s[row];
    float* rowp = attn_b + (size_t)row * 1024;
#pragma unroll
    for (int i = 0; i < 8; ++i) {
      int c8 = (cb + i * 16) * 8;
      bf16x8 ev = *reinterpret_cast<const bf16x8*>(&E_lds[row][c8]);
      f32x4 o0, o1;
#pragma unroll
      for (int j = 0; j < 4; ++j) o0[j] = bf2f((unsigned short)ev[j]) * sc;
#pragma unroll
      for (int j = 0; j < 4; ++j) o1[j] = bf2f((unsigned short)ev[4 + j]) * sc;
      *reinterpret_cast<f32x4*>(rowp + c8) = o0;
      *reinterpret_cast<f32x4*>(rowp + c8 + 4) = o1;
    }
  }

  // ---- phase 3: PV from E_lds, 2-stage register pipeline ----
  f32x4 acc[2][4];
#pragma unroll
  for (int mf = 0; mf < 2; ++mf)
#pragma unroll
    for (int nfo = 0; nfo < 4; ++nfo) acc[mf][nfo] = (f32x4){0.f, 0.f, 0.f, 0.f};

  const unsigned short* vbase = vt + (size_t)b * 1024 + (size_t)(w * 64 + lr) * 8192 + lg * 8;

  bf16x8 bvA[4], bvB[4], paA[2], paB[2];
#pragma unroll
  for (int nfo = 0; nfo < 4; ++nfo)
    bvA[nfo] = *reinterpret_cast<const bf16x8*>(vbase + (size_t)(nfo * 16) * 8192);
#pragma unroll
  for (int mf = 0; mf < 2; ++mf)
    paA[mf] = *reinterpret_cast<const bf16x8*>(&E_lds[mf * 16 + lr][lg * 8]);

  for (int ks = 0; ks < 32; ks += 2) {
    // prefetch stage B (ks+1)
#pragma unroll
    for (int nfo = 0; nfo < 4; ++nfo)
      bvB[nfo] = *reinterpret_cast<const bf16x8*>(vbase + (size_t)(nfo * 16) * 8192 + (ks + 1) * 32);
#pragma unroll
    for (int mf = 0; mf < 2; ++mf)
      paB[mf] = *reinterpret_cast<const bf16x8*>(&E_lds[mf * 16 + lr][(ks + 1) * 32 + lg * 8]);

    __builtin_amdgcn_s_setprio(1);
#pragma unroll
    for (int nfo = 0; nfo < 4; ++nfo)
#pragma unroll
      for (int mf = 0; mf < 2; ++mf)
        acc[mf][nfo] = __builtin_amdgcn_mfma_f32_16x16x32_bf16(paA[mf], bvA[nfo], acc[mf][nfo], 0, 0, 0);
    __builtin_amdgcn_s_setprio(0);

    // prefetch stage A (ks+2)
    if (ks + 2 < 32) {
#pragma unroll
      for (int nfo = 0; nfo < 4; ++nfo)
        bvA[nfo] = *reinterpret_cast<const bf16x8*>(vbase + (size_t)(nfo * 16) * 8192 + (ks + 2) * 32);
#pragma unroll
      for (int mf = 0; mf < 2; ++mf)
        paA[mf] = *reinterpret_cast<const bf16x8*>(&E_lds[mf * 16 + lr][(ks + 2) * 32 + lg * 8]);
    }

    __builtin_amdgcn_s_setprio(1);
#pragma unroll
    for (int nfo = 0; nfo < 4; ++nfo)
#pragma unroll
      for (int mf = 0; mf < 2; ++mf)
        acc[mf][nfo] = __builtin_amdgcn_mfma_f32_16x16x32_bf16(paB[mf], bvB[nfo], acc[mf][nfo], 0, 0, 0);
    __builtin_amdgcn_s_setprio(0);
  }

#pragma unroll
  for (int mf = 0; mf < 2; ++mf)
#pragma unroll
    for (int nfo = 0; nfo < 4; ++nfo)
#pragma unroll
      for (int r = 0; r < 4; ++r) {
        int row = mf * 16 + lg * 4 + r;
        float val = acc[mf][nfo][r] * linv_s[row];
        o_ws[(size_t)(b * 1024 + q0 + row) * 8192 + h * 512 + w * 64 + nfo * 16 + lr] = f2bf(val);
      }
}

// ---------------- GEMM2: y = o @ W2 + b2  (BM=64, BN=128, BK=32, dbuf, 1 barrier/step) ----------------
__launch_bounds__(256)
__global__ void gemm2_kernel(const unsigned short* __restrict__ o_ws,
                             const unsigned short* __restrict__ w2t,
                             const float* __restrict__ b2,
                             float* __restrict__ y) {
  __shared__ unsigned short As[2][64 * 32];
  __shared__ unsigned short Bs[2][128 * 32];
  const int m0 = blockIdx.y * 64, n0 = blockIdx.x * 128;
  const int w = threadIdx.x >> 6, l = threadIdx.x & 63;
  const int wr = w >> 1, wc = w & 1, lr = l & 15, lg = l >> 4;

  f32x4 acc[2][4];
#pragma unroll
  for (int mi = 0; mi < 2; ++mi)
#pragma unroll
    for (int ni = 0; ni < 4; ++ni) acc[mi][ni] = (f32x4){0.f, 0.f, 0.f, 0.f};

  const int srow = threadIdx.x >> 2;        // 0..63
  const int scol = (threadIdx.x & 3) * 8;   // 0,8,16,24
  const unsigned short* gA = o_ws + (size_t)(m0 + srow) * 8192 + scol;
  const unsigned short* gB0 = w2t + (size_t)(n0 + srow) * 8192 + scol;
  const unsigned short* gB1 = w2t + (size_t)(n0 + 64 + srow) * 8192 + scol;
  // wave-uniform LDS bases (lane writes base + lane*16B)
  const int ldsoff = w * 512;               // = (w*16)*32

  auto STAGE = [&](int buf, int kt) {
    int k0 = kt * 32;
    gload_lds16(gA + k0, &As[buf][ldsoff]);
    gload_lds16(gB0 + k0, &Bs[buf][ldsoff]);
    gload_lds16(gB1 + k0, &Bs[buf][64 * 32 + ldsoff]);
  };

  auto COMPUTE = [&](int buf) {
    bf16x8 a[2], bb[4];
#pragma unroll
    for (int mi = 0; mi < 2; ++mi)
      a[mi] = *reinterpret_cast<const bf16x8*>(&As[buf][(wr * 32 + mi * 16 + lr) * 32 + lg * 8]);
#pragma unroll
    for (int ni = 0; ni < 4; ++ni)
      bb[ni] = *reinterpret_cast<const bf16x8*>(&Bs[buf][(wc * 64 + ni * 16 + lr) * 32 + lg * 8]);
    __builtin_amdgcn_s_setprio(1);
#pragma unroll
    for (int mi = 0; mi < 2; ++mi)
#pragma unroll
      for (int ni = 0; ni < 4; ++ni)
        acc[mi][ni] = __builtin_amdgcn_mfma_f32_16x16x32_bf16(a[mi], bb[ni], acc[mi][ni], 0, 0, 0);
    __builtin_amdgcn_s_setprio(0);
  };

  STAGE(0, 0);
  __syncthreads();
  int cur = 0;
  for (int kt = 0; kt < 255; ++kt) {
    STAGE(cur ^ 1, kt + 1);   // issue next-tile loads BEFORE compute
    COMPUTE(cur);
    __syncthreads();          // drains vmcnt: next buffer ready, cur safe to overwrite
    cur ^= 1;
  }
  COMPUTE(cur);

#pragma unroll
  for (int mi = 0; mi < 2; ++mi)
#pragma unroll
    for (int ni = 0; ni < 4; ++ni) {
      int col = n0 + wc * 64 + ni * 16 + lr;
      float bias = b2[col];
#pragma unroll
      for (int r = 0; r < 4; ++r)
        y[(size_t)(m0 + wr * 32 + mi * 16 + lg * 4 + r) * 512 + col] = acc[mi][ni][r] + bias;
    }
}

// ---------------- launch ----------------
extern "C" void kernel_launch(void* const* d_in, const int* in_sizes, int n_in,
                              void* d_out, int out_size, void* d_ws, size_t ws_size,
                              hipStream_t stream) {
  const float* v   = (const float*)d_in[0];
  const int*   pad = (const int*)d_in[1];
  const float* W1  = (const float*)d_in[2];
  const float* b1  = (const float*)d_in[3];
  const float* W2  = (const float*)d_in[4];
  const float* b2  = (const float*)d_in[5];
  float* out  = (float*)d_out;
  float* attn = out + (size_t)8 * 1024 * 512;

  char* ws = (char*)d_ws;
  unsigned short* w1t  = (unsigned short*)(ws);              //  2 MB  [2048][512]
  unsigned short* w2t  = (unsigned short*)(ws + 2097152);    //  8 MB  [512][8192]
  unsigned short* vt   = (unsigned short*)(ws + 10485760);   //  8 MB  [512][8192]
  unsigned short* vbf  = (unsigned short*)(ws + 18874368);   //  8 MB  [8192][512]
  unsigned short* q_ws = (unsigned short*)(ws + 27262976);   // 16 MB  [128][1024][64]
  unsigned short* k_ws = (unsigned short*)(ws + 44040192);   // 16 MB  [128][1024][64]
  unsigned short* o_ws = (unsigned short*)(ws + 60817408);   // 134 MB [8192][8192]

  transpose_cvt_kernel<<<dim3(64, 16), 256, 0, stream>>>(W1, w1t, 512, 2048);
  transpose_cvt_kernel<<<dim3(16, 256), 256, 0, stream>>>(W2, w2t, 8192, 512);
  transpose_cvt_kernel<<<dim3(16, 256), 256, 0, stream>>>(v, vt, 8192, 512);
  cvt_bf16_kernel<<<4096, 256, 0, stream>>>(v, vbf, 1048576);
  gemm1_kernel<<<dim3(16, 64), 256, 0, stream>>>(vbf, w1t, b1, q_ws, k_ws);
  attn_kernel<<<4096, 512, 0, stream>>>(q_ws, k_ws, vt, pad, attn, o_ws);
  gemm2_kernel<<<dim3(4, 128), 256, 0, stream>>>(o_ws, w2t, b2, out);
}